// Round 1
// 99.703 us; speedup vs baseline: 1.0395x; 1.0395x over previous
//
#include <hip/hip_runtime.h>
#include <hip/hip_bf16.h>

// Problem constants (B=1). All inputs/outputs are float32.
#define HH   96
#define WW   96
#define NPIX 9216          // 96*96
#define CH   128
#define NH   8
#define HD   16
#define KS   8

#define NEPIX   2304       // 48*48 even-even grid (k/v only ever read there)
#define NPOS    120        // 8 window rows x 15 window cols per 16-px segment
#define KVPITCH 40         // attn LDS pitch in channels (80B/pos)
#define QTPITCH 136        // conv q-tile pitch (ch)
#define KVTPITCH 264       // conv kv-tile pitch (ch, k+v = 256 + pad)

__device__ __forceinline__ unsigned short f2bf(float f) {
    __hip_bfloat16 b = __float2bfloat16(f);
    union { __hip_bfloat16 b; unsigned short u; } cv; cv.b = b; return cv.u;
}
// unpack uint4 = 8 bf16 -> 8 fp32
__device__ __forceinline__ void u4_to_f8(uint4 u, float* f) {
    f[0] = __uint_as_float(u.x << 16); f[1] = __uint_as_float(u.x & 0xffff0000u);
    f[2] = __uint_as_float(u.y << 16); f[3] = __uint_as_float(u.y & 0xffff0000u);
    f[4] = __uint_as_float(u.z << 16); f[5] = __uint_as_float(u.z & 0xffff0000u);
    f[6] = __uint_as_float(u.w << 16); f[7] = __uint_as_float(u.w & 0xffff0000u);
}

// ---------------------------------------------------------------------------
// K1: depthwise 3x3 conv. q computed at ALL pixels -> q_pm [NPIX][CH];
// k/v computed ONLY at even-even pixels (the only ones attention reads,
// since stride=2 centers + dil=2 windows land on even coords) -> compact
// kv_pm [2][NEPIX][CH]. (unchanged, R12-proven)
// ---------------------------------------------------------------------------
__global__ __launch_bounds__(256) void conv_kernel(
    const float* __restrict__ x,        // [128][96][96]
    const float* __restrict__ w,        // [384][1][3][3]
    const float* __restrict__ bias,     // [384]
    unsigned short* __restrict__ q_pm,  // [NPIX][CH] bf16
    unsigned short* __restrict__ kv_pm) // [2][NEPIX][CH] bf16
{
    __shared__ unsigned short qt [24 * QTPITCH];    // 6,528 B
    __shared__ unsigned short kvt[12 * KVTPITCH];   // 6,336 B

    const int row = blockIdx.x >> 2;    // 0..95
    const int qtr = blockIdx.x & 3;     // 0..3
    const int j0q = qtr * 24;
    const int tid = threadIdx.x;
    const int g   = tid >> 1;           // 0..127 input channel / group
    const int sh  = tid & 1;            // 0/1 -> 12 px each
    const int j0  = j0q + sh * 12;      // even (24-multiples + 0/12)
    const bool kvrow = (row & 1) == 0;  // block-uniform

    const float* xg = x + g * NPIX;

    float xr[3][14];
    #pragma unroll
    for (int dr = 0; dr < 3; ++dr) {
        const int r = row + dr - 1;
        if (r >= 0 && r < HH) {
            #pragma unroll
            for (int m = 0; m < 14; ++m) {
                const int j = j0 + m - 1;
                xr[dr][m] = (j >= 0 && j < WW) ? xg[r * WW + j] : 0.f;
            }
        } else {
            #pragma unroll
            for (int m = 0; m < 14; ++m) xr[dr][m] = 0.f;
        }
    }

    #pragma unroll
    for (int dt = 0; dt < 3; ++dt) {
        const int o = 3 * g + dt;       // conv out-channel (group g)
        const int t = o >> 7;           // 0=q, 1=k, 2=v
        const int c = o & 127;
        float w9[9];
        #pragma unroll
        for (int k = 0; k < 9; ++k) w9[k] = w[o * 9 + k];
        const float b = bias[o];

        if (t == 0) {
            #pragma unroll
            for (int px = 0; px < 12; ++px) {
                float acc = b;
                #pragma unroll
                for (int kh = 0; kh < 3; ++kh)
                    #pragma unroll
                    for (int kw = 0; kw < 3; ++kw)
                        acc += xr[kh][px + kw] * w9[kh * 3 + kw];
                qt[(sh * 12 + px) * QTPITCH + c] = f2bf(acc);
            }
        } else if (kvrow) {
            #pragma unroll
            for (int pe = 0; pe < 6; ++pe) {        // even px only
                const int px = pe * 2;
                float acc = b;
                #pragma unroll
                for (int kh = 0; kh < 3; ++kh)
                    #pragma unroll
                    for (int kw = 0; kw < 3; ++kw)
                        acc += xr[kh][px + kw] * w9[kh * 3 + kw];
                kvt[(sh * 6 + pe) * KVTPITCH + (t - 1) * CH + c] = f2bf(acc);
            }
        }
    }

    __syncthreads();

    // write q: 24 px x 16 uint4 = 384 tasks; kv (even rows): +384 tasks
    const int ntask = kvrow ? 768 : 384;
    #pragma unroll
    for (int it = 0; it < 3; ++it) {
        const int idx = it * 256 + tid;
        if (idx < 384) {
            const int px  = idx >> 4;           // 0..23
            const int c8  = (idx & 15) * 8;
            const uint4 v = *(const uint4*)&qt[px * QTPITCH + c8];
            *(uint4*)(q_pm + ((size_t)(row * WW) + j0q + px) * CH + c8) = v;
        } else if (idx < ntask) {
            const int k2  = idx - 384;
            const int epx = k2 >> 5;            // 0..11
            const int c32 = (k2 & 31) * 8;      // 0..255 ch (k then v)
            const int t1  = c32 >> 7;           // 0=k, 1=v
            const int c   = c32 & 127;
            const uint4 v = *(const uint4*)&kvt[epx * KVTPITCH + c32];
            *(uint4*)(kv_pm + ((size_t)t1 * NEPIX + (row >> 1) * 48
                               + (j0q >> 1) + epx) * CH + c) = v;
        }
    }
}

// ---------------------------------------------------------------------------
// K2: neighborhood attention, head-pair blocks (unchanged, R12-proven).
// Grid (576 segs, 4 head-pairs); block = 256 thr = 16 px x 2 heads x 8 r.
// ---------------------------------------------------------------------------
__global__ __launch_bounds__(256) void attn_kernel(
    const unsigned short* __restrict__ q_pm,    // [NPIX][CH] bf16
    const unsigned short* __restrict__ kv_pm,   // [2][NEPIX][CH] bf16
    float* __restrict__ a_t)                    // [CH][NPIX] fp32
{
    __shared__ unsigned short kv[2][NPOS * KVPITCH];   // 19,200 B

    const int tid = threadIdx.x;
    const int seg = blockIdx.x;                 // 0..575
    const int hp  = blockIdx.y;                 // head pair 0..3
    const int i   = seg / 6;                    // image row
    const int j0  = (seg - i * 6) * 16;
    const int rs     = 2 * min(max(i / 2 - 3, 0), 40);
    const int cs_min = 2 * min(max(j0 / 2 - 3, 0), 40);
    const int er0 = rs >> 1;                    // compact window row base
    const int ec0 = cs_min >> 1;                // compact window col base

    // ---- stage K,V head-pair slice: 960 uint4 tasks ----
    #pragma unroll
    for (int it = 0; it < 4; ++it) {
        const int idx = it * 256 + tid;
        if (idx < 960) {
            const int kvsel = idx / 480;
            const int rem   = idx - kvsel * 480;
            const int pos   = rem >> 2;
            const int sub   = rem & 3;
            const int p     = pos / 15;
            const int cc    = pos - p * 15;
            const int ec    = min(ec0 + cc, 47);        // clamp: cc>=11 at the
            const int ep    = (er0 + p) * 48 + ec;      // right edge is unused
            *(uint4*)&kv[kvsel][pos * KVPITCH + sub * 8] =
                *(const uint4*)(kv_pm + ((size_t)kvsel * NEPIX + ep) * CH
                                + hp * 32 + sub * 8);
        }
    }

    // ---- per-thread coordinates: lane = r*8 + hh*4 + px_lo ----
    const int lane  = tid & 63;
    const int wave  = tid >> 6;                 // 0..3
    const int r     = lane >> 3;                // window-row split
    const int hh    = (lane >> 2) & 1;          // head within pair
    const int px    = wave * 4 + (lane & 3);    // 0..15
    const int h     = hp * 2 + hh;
    const int pix   = seg * 16 + px;
    const int j     = j0 + px;
    const int ci0   = (2 * min(max(j / 2 - 3, 0), 40) - cs_min) >> 1;  // 0..7

    float qr[HD];
    {
        const unsigned short* qp = q_pm + (size_t)pix * CH + h * HD;
        u4_to_f8(*(const uint4*)qp, qr);
        u4_to_f8(*(const uint4*)(qp + 8), qr + 8);
        #pragma unroll
        for (int d = 0; d < HD; ++d) qr[d] *= 0.25f;   // HD^-0.5
    }

    __syncthreads();

    const int posr = r * 15 + ci0;
    float lg[KS];
    float m = -1e30f;
    #pragma unroll
    for (int q = 0; q < KS; ++q) {
        const unsigned short* kp = &kv[0][(posr + q) * KVPITCH + hh * HD];
        float kf[HD];
        u4_to_f8(*(const uint4*)kp, kf);
        u4_to_f8(*(const uint4*)(kp + 8), kf + 8);
        float acc = 0.f;
        #pragma unroll
        for (int d = 0; d < HD; ++d) acc += qr[d] * kf[d];
        lg[q] = acc;
        m = fmaxf(m, acc);
    }

    float s = 0.f;
    #pragma unroll
    for (int q = 0; q < KS; ++q) { lg[q] = __expf(lg[q] - m); s += lg[q]; }

    float o[HD];
    #pragma unroll
    for (int d = 0; d < HD; ++d) o[d] = 0.f;
    #pragma unroll
    for (int q = 0; q < KS; ++q) {
        const unsigned short* vp = &kv[1][(posr + q) * KVPITCH + hh * HD];
        float vf[HD];
        u4_to_f8(*(const uint4*)vp, vf);
        u4_to_f8(*(const uint4*)(vp + 8), vf + 8);
        const float wgt = lg[q];
        #pragma unroll
        for (int d = 0; d < HD; ++d) o[d] += wgt * vf[d];
    }

    #pragma unroll
    for (int mask = 8; mask <= 32; mask <<= 1) {
        const float m2 = __shfl_xor(m, mask);
        const float s2 = __shfl_xor(s, mask);
        const float mn = fmaxf(m, m2);
        const float ea = __expf(m - mn);
        const float eb = __expf(m2 - mn);
        s = s * ea + s2 * eb;
        #pragma unroll
        for (int d = 0; d < HD; ++d) {
            const float o2 = __shfl_xor(o[d], mask);
            o[d] = o[d] * ea + o2 * eb;
        }
        m = mn;
    }
    const float inv = 1.f / s;

    a_t[(size_t)(h * HD + 2 * r)     * NPIX + pix] = o[2 * r]     * inv;
    a_t[(size_t)(h * HD + 2 * r + 1) * NPIX + pix] = o[2 * r + 1] * inv;
}

// ---------------------------------------------------------------------------
// K3 (NEW): 1x1 projection as a single-pass GEMM.
// out[o][p] = pb[o] + sum_c pw[o][c] * a_t[c][p].
// Each block covers ALL 128 output channels for a 32-px stripe, so a_t is
// read from global exactly ONCE total (4.72 MB, was 64x = 302 MB through
// L2/L3 — the 9-stripe x 8-XCD coprime interleave thrashed every L2).
// LDS a-tile [128 c][36 pitch] f32 (18.4 KB): pitch 36 -> bank-conflict-free
// b128 staging writes (banks rotate by 4c) and broadcast b128 reads.
// Thread tile: 4 o x 4 px (16 fp32 accumulators, fp32 math — accuracy
// identical to baseline). w reads: float4 along c, 8 px-threads broadcast
// per address -> 18 MB of pure L2 traffic across 288 blocks.
// Grid 288 x 256 thr; only 32 CUs get a 2nd block (12% tail imbalance).
// ---------------------------------------------------------------------------
__global__ __launch_bounds__(256) void proj_kernel(
    const float* __restrict__ a_t,      // [CH][NPIX]
    const float* __restrict__ pw,       // [128][128] ([o][c])
    const float* __restrict__ pb,       // [128]
    float* __restrict__ out)            // [128][NPIX]
{
    __shared__ float at[CH][36];        // 18,432 B

    const int tid = threadIdx.x;
    const int px0 = blockIdx.x * 32;

    // stage a_t[0..127][px0..px0+31]: 1024 float4 tasks, 4 per thread
    #pragma unroll
    for (int it = 0; it < 4; ++it) {
        const int idx = it * 256 + tid;     // 0..1023
        const int c   = idx >> 3;           // 0..127
        const int p4  = (idx & 7) * 4;      // 0,4,..,28
        *(float4*)&at[c][p4] =
            *(const float4*)(a_t + (size_t)c * NPIX + px0 + p4);
    }
    __syncthreads();

    const int og = tid >> 3;                // 0..31 -> 4 o each
    const int o0 = og * 4;
    const int p0 = (tid & 7) * 4;           // 0..28

    float acc[4][4];
    #pragma unroll
    for (int i = 0; i < 4; ++i) {
        const float b = pb[o0 + i];
        #pragma unroll
        for (int j = 0; j < 4; ++j) acc[i][j] = b;
    }

    #pragma unroll 2
    for (int c0 = 0; c0 < CH; c0 += 4) {
        float4 wv[4];                       // w[o0+i][c0..c0+3]
        #pragma unroll
        for (int i = 0; i < 4; ++i)
            wv[i] = *(const float4*)(pw + (size_t)(o0 + i) * CH + c0);
        float4 av[4];                       // at[c0+k][p0..p0+3]
        #pragma unroll
        for (int k = 0; k < 4; ++k)
            av[k] = *(const float4*)&at[c0 + k][p0];
        #pragma unroll
        for (int i = 0; i < 4; ++i) {
            acc[i][0] += wv[i].x * av[0].x; acc[i][1] += wv[i].x * av[0].y;
            acc[i][2] += wv[i].x * av[0].z; acc[i][3] += wv[i].x * av[0].w;
            acc[i][0] += wv[i].y * av[1].x; acc[i][1] += wv[i].y * av[1].y;
            acc[i][2] += wv[i].y * av[1].z; acc[i][3] += wv[i].y * av[1].w;
            acc[i][0] += wv[i].z * av[2].x; acc[i][1] += wv[i].z * av[2].y;
            acc[i][2] += wv[i].z * av[2].z; acc[i][3] += wv[i].z * av[2].w;
            acc[i][0] += wv[i].w * av[3].x; acc[i][1] += wv[i].w * av[3].y;
            acc[i][2] += wv[i].w * av[3].z; acc[i][3] += wv[i].w * av[3].w;
        }
    }

    #pragma unroll
    for (int i = 0; i < 4; ++i)
        *(float4*)(out + (size_t)(o0 + i) * NPIX + px0 + p0)
            = make_float4(acc[i][0], acc[i][1], acc[i][2], acc[i][3]);
}

// ---------------------------------------------------------------------------
extern "C" void kernel_launch(void* const* d_in, const int* in_sizes, int n_in,
                              void* d_out, int out_size, void* d_ws, size_t ws_size,
                              hipStream_t stream)
{
    const float* x      = (const float*)d_in[0];
    const float* qkv_w  = (const float*)d_in[1];
    const float* qkv_b  = (const float*)d_in[2];
    const float* proj_w = (const float*)d_in[3];
    const float* proj_b = (const float*)d_in[4];
    float* out = (float*)d_out;

    // ws: [q_pm 2.36 MB][kv_pm 1.18 MB][a_t 4.72 MB]
    unsigned short* q_pm  = (unsigned short*)d_ws;             // [NPIX][CH]
    unsigned short* kv_pm = q_pm + (size_t)NPIX * CH;          // [2][NEPIX][CH]
    float*          a_t   = (float*)(kv_pm + (size_t)2 * NEPIX * CH);

    conv_kernel<<<384, 256, 0, stream>>>(x, qkv_w, qkv_b, q_pm, kv_pm);
    attn_kernel<<<dim3(576, 4), 256, 0, stream>>>(q_pm, kv_pm, a_t);
    proj_kernel<<<288, 256, 0, stream>>>(a_t, proj_w, proj_b, out);
}

// Round 2
// 99.569 us; speedup vs baseline: 1.0409x; 1.0013x over previous
//
#include <hip/hip_runtime.h>
#include <hip/hip_bf16.h>

// Problem constants (B=1). All inputs/outputs are float32.
#define HH   96
#define WW   96
#define NPIX 9216          // 96*96
#define CH   128
#define NH   8
#define HD   16
#define KS   8

#define NEPIX   2304       // 48*48 even-even grid (k/v only ever read there)
#define NPOS    120        // 8 window rows x 15 window cols per 16-px segment
#define KVPITCH 40         // attn LDS pitch in channels (80B/pos)
#define QTPITCH 136        // conv q-tile pitch (ch)
#define KVTPITCH 264       // conv kv-tile pitch (ch, k+v = 256 + pad)
#define XPITCH  97         // conv input-slab pitch (floats per channel)

__device__ __forceinline__ unsigned short f2bf(float f) {
    __hip_bfloat16 b = __float2bfloat16(f);
    union { __hip_bfloat16 b; unsigned short u; } cv; cv.b = b; return cv.u;
}
// unpack uint4 = 8 bf16 -> 8 fp32
__device__ __forceinline__ void u4_to_f8(uint4 u, float* f) {
    f[0] = __uint_as_float(u.x << 16); f[1] = __uint_as_float(u.x & 0xffff0000u);
    f[2] = __uint_as_float(u.y << 16); f[3] = __uint_as_float(u.y & 0xffff0000u);
    f[4] = __uint_as_float(u.z << 16); f[5] = __uint_as_float(u.z & 0xffff0000u);
    f[6] = __uint_as_float(u.w << 16); f[7] = __uint_as_float(u.w & 0xffff0000u);
}

// ---------------------------------------------------------------------------
// K1: depthwise 3x3 conv. q at ALL pixels -> q_pm [NPIX][CH]; k/v ONLY at
// even-even pixels -> compact kv_pm [2][NEPIX][CH].
// NEW: input slab x[128c][3r][32 cols] staged into LDS via 12 coalesced
// float4 loads/thread (was 42 uncoalesced scalar dword loads/thread — each
// instr touched 64 distinct cache lines). Pitch 97 floats/channel: compute
// reads are <=2-way bank-aliased (free), stage writes conflict-free.
// Per-output conv math is bit-identical to the proven kernel.
// ---------------------------------------------------------------------------
__global__ __launch_bounds__(256) void conv_kernel(
    const float* __restrict__ x,        // [128][96][96]
    const float* __restrict__ w,        // [384][1][3][3]
    const float* __restrict__ bias,     // [384]
    unsigned short* __restrict__ q_pm,  // [NPIX][CH] bf16
    unsigned short* __restrict__ kv_pm) // [2][NEPIX][CH] bf16
{
    __shared__ float ldsx[128 * XPITCH];            // 49,664 B
    __shared__ unsigned short qt [24 * QTPITCH];    // 6,528 B
    __shared__ unsigned short kvt[12 * KVTPITCH];   // 6,336 B

    const int row = blockIdx.x >> 2;    // 0..95
    const int qtr = blockIdx.x & 3;     // 0..3
    const int j0q = qtr * 24;
    const int tid = threadIdx.x;
    const int g   = tid >> 1;           // 0..127 input channel / group
    const int sh  = tid & 1;            // 0/1 -> 12 px each
    const bool kvrow = (row & 1) == 0;  // block-uniform

    // ---- stage x[c][row-1..row+1][j0q-4..j0q+27] -> LDS, coalesced ----
    // 3072 float4 tasks: t = r*1024 + c*8 + s4 (all shifts, no divides).
    // OOB (row edge / col edge incl. the j=96..99 tail) -> zero.
    #pragma unroll
    for (int it = 0; it < 12; ++it) {
        const int t  = it * 256 + tid;      // 0..3071
        const int r  = t >> 10;             // 0..2
        const int c  = (t >> 3) & 127;      // 0..127
        const int s4 = t & 7;               // 0..7
        const int rg = row + r - 1;
        const int j  = j0q - 4 + s4 * 4;    // 4-aligned; fully in or out
        float4 v = make_float4(0.f, 0.f, 0.f, 0.f);
        if (rg >= 0 && rg < HH && j >= 0 && j < WW)
            v = *(const float4*)(x + (size_t)c * NPIX + rg * WW + j);
        *(float4*)&ldsx[c * XPITCH + r * 32 + s4 * 4] = v;
    }
    __syncthreads();

    // ---- per-thread window from LDS: s = j - (j0q-4) = 3 + sh*12 + m ----
    float xr[3][14];
    {
        const float* xg_l = &ldsx[g * XPITCH + 3 + sh * 12];
        #pragma unroll
        for (int dr = 0; dr < 3; ++dr)
            #pragma unroll
            for (int m = 0; m < 14; ++m)
                xr[dr][m] = xg_l[dr * 32 + m];
    }

    #pragma unroll
    for (int dt = 0; dt < 3; ++dt) {
        const int o = 3 * g + dt;       // conv out-channel (group g)
        const int t = o >> 7;           // 0=q, 1=k, 2=v
        const int c = o & 127;
        float w9[9];
        #pragma unroll
        for (int k = 0; k < 9; ++k) w9[k] = w[o * 9 + k];
        const float b = bias[o];

        if (t == 0) {
            #pragma unroll
            for (int px = 0; px < 12; ++px) {
                float acc = b;
                #pragma unroll
                for (int kh = 0; kh < 3; ++kh)
                    #pragma unroll
                    for (int kw = 0; kw < 3; ++kw)
                        acc += xr[kh][px + kw] * w9[kh * 3 + kw];
                qt[(sh * 12 + px) * QTPITCH + c] = f2bf(acc);
            }
        } else if (kvrow) {
            #pragma unroll
            for (int pe = 0; pe < 6; ++pe) {        // even px only
                const int px = pe * 2;
                float acc = b;
                #pragma unroll
                for (int kh = 0; kh < 3; ++kh)
                    #pragma unroll
                    for (int kw = 0; kw < 3; ++kw)
                        acc += xr[kh][px + kw] * w9[kh * 3 + kw];
                kvt[(sh * 6 + pe) * KVTPITCH + (t - 1) * CH + c] = f2bf(acc);
            }
        }
    }

    __syncthreads();

    // write q: 24 px x 16 uint4 = 384 tasks; kv (even rows): +384 tasks
    const int ntask = kvrow ? 768 : 384;
    #pragma unroll
    for (int it = 0; it < 3; ++it) {
        const int idx = it * 256 + tid;
        if (idx < 384) {
            const int px  = idx >> 4;           // 0..23
            const int c8  = (idx & 15) * 8;
            const uint4 v = *(const uint4*)&qt[px * QTPITCH + c8];
            *(uint4*)(q_pm + ((size_t)(row * WW) + j0q + px) * CH + c8) = v;
        } else if (idx < ntask) {
            const int k2  = idx - 384;
            const int epx = k2 >> 5;            // 0..11
            const int c32 = (k2 & 31) * 8;      // 0..255 ch (k then v)
            const int t1  = c32 >> 7;           // 0=k, 1=v
            const int c   = c32 & 127;
            const uint4 v = *(const uint4*)&kvt[epx * KVTPITCH + c32];
            *(uint4*)(kv_pm + ((size_t)t1 * NEPIX + (row >> 1) * 48
                               + (j0q >> 1) + epx) * CH + c) = v;
        }
    }
}

// ---------------------------------------------------------------------------
// K2: neighborhood attention, head-pair blocks (unchanged, R12-proven).
// Grid (576 segs, 4 head-pairs); block = 256 thr = 16 px x 2 heads x 8 r.
// ---------------------------------------------------------------------------
__global__ __launch_bounds__(256) void attn_kernel(
    const unsigned short* __restrict__ q_pm,    // [NPIX][CH] bf16
    const unsigned short* __restrict__ kv_pm,   // [2][NEPIX][CH] bf16
    float* __restrict__ a_t)                    // [CH][NPIX] fp32
{
    __shared__ unsigned short kv[2][NPOS * KVPITCH];   // 19,200 B

    const int tid = threadIdx.x;
    const int seg = blockIdx.x;                 // 0..575
    const int hp  = blockIdx.y;                 // head pair 0..3
    const int i   = seg / 6;                    // image row
    const int j0  = (seg - i * 6) * 16;
    const int rs     = 2 * min(max(i / 2 - 3, 0), 40);
    const int cs_min = 2 * min(max(j0 / 2 - 3, 0), 40);
    const int er0 = rs >> 1;                    // compact window row base
    const int ec0 = cs_min >> 1;                // compact window col base

    // ---- stage K,V head-pair slice: 960 uint4 tasks ----
    #pragma unroll
    for (int it = 0; it < 4; ++it) {
        const int idx = it * 256 + tid;
        if (idx < 960) {
            const int kvsel = idx / 480;
            const int rem   = idx - kvsel * 480;
            const int pos   = rem >> 2;
            const int sub   = rem & 3;
            const int p     = pos / 15;
            const int cc    = pos - p * 15;
            const int ec    = min(ec0 + cc, 47);        // clamp: cc>=11 at the
            const int ep    = (er0 + p) * 48 + ec;      // right edge is unused
            *(uint4*)&kv[kvsel][pos * KVPITCH + sub * 8] =
                *(const uint4*)(kv_pm + ((size_t)kvsel * NEPIX + ep) * CH
                                + hp * 32 + sub * 8);
        }
    }

    // ---- per-thread coordinates: lane = r*8 + hh*4 + px_lo ----
    const int lane  = tid & 63;
    const int wave  = tid >> 6;                 // 0..3
    const int r     = lane >> 3;                // window-row split
    const int hh    = (lane >> 2) & 1;          // head within pair
    const int px    = wave * 4 + (lane & 3);    // 0..15
    const int h     = hp * 2 + hh;
    const int pix   = seg * 16 + px;
    const int j     = j0 + px;
    const int ci0   = (2 * min(max(j / 2 - 3, 0), 40) - cs_min) >> 1;  // 0..7

    float qr[HD];
    {
        const unsigned short* qp = q_pm + (size_t)pix * CH + h * HD;
        u4_to_f8(*(const uint4*)qp, qr);
        u4_to_f8(*(const uint4*)(qp + 8), qr + 8);
        #pragma unroll
        for (int d = 0; d < HD; ++d) qr[d] *= 0.25f;   // HD^-0.5
    }

    __syncthreads();

    const int posr = r * 15 + ci0;
    float lg[KS];
    float m = -1e30f;
    #pragma unroll
    for (int q = 0; q < KS; ++q) {
        const unsigned short* kp = &kv[0][(posr + q) * KVPITCH + hh * HD];
        float kf[HD];
        u4_to_f8(*(const uint4*)kp, kf);
        u4_to_f8(*(const uint4*)(kp + 8), kf + 8);
        float acc = 0.f;
        #pragma unroll
        for (int d = 0; d < HD; ++d) acc += qr[d] * kf[d];
        lg[q] = acc;
        m = fmaxf(m, acc);
    }

    float s = 0.f;
    #pragma unroll
    for (int q = 0; q < KS; ++q) { lg[q] = __expf(lg[q] - m); s += lg[q]; }

    float o[HD];
    #pragma unroll
    for (int d = 0; d < HD; ++d) o[d] = 0.f;
    #pragma unroll
    for (int q = 0; q < KS; ++q) {
        const unsigned short* vp = &kv[1][(posr + q) * KVPITCH + hh * HD];
        float vf[HD];
        u4_to_f8(*(const uint4*)vp, vf);
        u4_to_f8(*(const uint4*)(vp + 8), vf + 8);
        const float wgt = lg[q];
        #pragma unroll
        for (int d = 0; d < HD; ++d) o[d] += wgt * vf[d];
    }

    #pragma unroll
    for (int mask = 8; mask <= 32; mask <<= 1) {
        const float m2 = __shfl_xor(m, mask);
        const float s2 = __shfl_xor(s, mask);
        const float mn = fmaxf(m, m2);
        const float ea = __expf(m - mn);
        const float eb = __expf(m2 - mn);
        s = s * ea + s2 * eb;
        #pragma unroll
        for (int d = 0; d < HD; ++d) {
            const float o2 = __shfl_xor(o[d], mask);
            o[d] = o[d] * ea + o2 * eb;
        }
        m = mn;
    }
    const float inv = 1.f / s;

    a_t[(size_t)(h * HD + 2 * r)     * NPIX + pix] = o[2 * r]     * inv;
    a_t[(size_t)(h * HD + 2 * r + 1) * NPIX + pix] = o[2 * r + 1] * inv;
}

// ---------------------------------------------------------------------------
// K3: 1x1 projection, single-pass GEMM (unchanged from round 0).
// a_t read from global exactly once; LDS tile [128][36] f32.
// ---------------------------------------------------------------------------
__global__ __launch_bounds__(256) void proj_kernel(
    const float* __restrict__ a_t,      // [CH][NPIX]
    const float* __restrict__ pw,       // [128][128] ([o][c])
    const float* __restrict__ pb,       // [128]
    float* __restrict__ out)            // [128][NPIX]
{
    __shared__ float at[CH][36];        // 18,432 B

    const int tid = threadIdx.x;
    const int px0 = blockIdx.x * 32;

    // stage a_t[0..127][px0..px0+31]: 1024 float4 tasks, 4 per thread
    #pragma unroll
    for (int it = 0; it < 4; ++it) {
        const int idx = it * 256 + tid;     // 0..1023
        const int c   = idx >> 3;           // 0..127
        const int p4  = (idx & 7) * 4;      // 0,4,..,28
        *(float4*)&at[c][p4] =
            *(const float4*)(a_t + (size_t)c * NPIX + px0 + p4);
    }
    __syncthreads();

    const int og = tid >> 3;                // 0..31 -> 4 o each
    const int o0 = og * 4;
    const int p0 = (tid & 7) * 4;           // 0..28

    float acc[4][4];
    #pragma unroll
    for (int i = 0; i < 4; ++i) {
        const float b = pb[o0 + i];
        #pragma unroll
        for (int j = 0; j < 4; ++j) acc[i][j] = b;
    }

    #pragma unroll 2
    for (int c0 = 0; c0 < CH; c0 += 4) {
        float4 wv[4];                       // w[o0+i][c0..c0+3]
        #pragma unroll
        for (int i = 0; i < 4; ++i)
            wv[i] = *(const float4*)(pw + (size_t)(o0 + i) * CH + c0);
        float4 av[4];                       // at[c0+k][p0..p0+3]
        #pragma unroll
        for (int k = 0; k < 4; ++k)
            av[k] = *(const float4*)&at[c0 + k][p0];
        #pragma unroll
        for (int i = 0; i < 4; ++i) {
            acc[i][0] += wv[i].x * av[0].x; acc[i][1] += wv[i].x * av[0].y;
            acc[i][2] += wv[i].x * av[0].z; acc[i][3] += wv[i].x * av[0].w;
            acc[i][0] += wv[i].y * av[1].x; acc[i][1] += wv[i].y * av[1].y;
            acc[i][2] += wv[i].y * av[1].z; acc[i][3] += wv[i].y * av[1].w;
            acc[i][0] += wv[i].z * av[2].x; acc[i][1] += wv[i].z * av[2].y;
            acc[i][2] += wv[i].z * av[2].z; acc[i][3] += wv[i].z * av[2].w;
            acc[i][0] += wv[i].w * av[3].x; acc[i][1] += wv[i].w * av[3].y;
            acc[i][2] += wv[i].w * av[3].z; acc[i][3] += wv[i].w * av[3].w;
        }
    }

    #pragma unroll
    for (int i = 0; i < 4; ++i)
        *(float4*)(out + (size_t)(o0 + i) * NPIX + px0 + p0)
            = make_float4(acc[i][0], acc[i][1], acc[i][2], acc[i][3]);
}

// ---------------------------------------------------------------------------
extern "C" void kernel_launch(void* const* d_in, const int* in_sizes, int n_in,
                              void* d_out, int out_size, void* d_ws, size_t ws_size,
                              hipStream_t stream)
{
    const float* x      = (const float*)d_in[0];
    const float* qkv_w  = (const float*)d_in[1];
    const float* qkv_b  = (const float*)d_in[2];
    const float* proj_w = (const float*)d_in[3];
    const float* proj_b = (const float*)d_in[4];
    float* out = (float*)d_out;

    // ws: [q_pm 2.36 MB][kv_pm 1.18 MB][a_t 4.72 MB]
    unsigned short* q_pm  = (unsigned short*)d_ws;             // [NPIX][CH]
    unsigned short* kv_pm = q_pm + (size_t)NPIX * CH;          // [2][NEPIX][CH]
    float*          a_t   = (float*)(kv_pm + (size_t)2 * NEPIX * CH);

    conv_kernel<<<384, 256, 0, stream>>>(x, qkv_w, qkv_b, q_pm, kv_pm);
    attn_kernel<<<dim3(576, 4), 256, 0, stream>>>(q_pm, kv_pm, a_t);
    proj_kernel<<<288, 256, 0, stream>>>(a_t, proj_w, proj_b, out);
}